// Round 2
// baseline (420.304 us; speedup 1.0000x reference)
//
#include <hip/hip_runtime.h>
#include <hip/hip_bf16.h>
#include <math.h>

#define NB 16
#define SS 64
#define HH 256
#define FAA 256

using short8 = __attribute__((ext_vector_type(8))) short;
using f32x4  = __attribute__((ext_vector_type(4))) float;

__device__ __forceinline__ unsigned short f2bf(float f) {
  union { float f; unsigned int u; } x; x.f = f;
  unsigned int u = x.u;
  return (unsigned short)((u + 0x7FFFu + ((u >> 16) & 1u)) >> 16);  // RNE
}
__device__ __forceinline__ unsigned int pk2(float a, float b) {
  return (unsigned int)f2bf(a) | ((unsigned int)f2bf(b) << 16);
}

// ---------------------------------------------------------------------------
// Prolog: fp32 -> bf16 conversions of weights / reused activations.
// wcat layout: rows 0..255 = Ur[o][k], rows 256..511 = U[o-256][k] (row-major K=256)
// ---------------------------------------------------------------------------
__global__ void prolog_cvt(const float* __restrict__ z1w, const float* __restrict__ Ur,
                           const float* __restrict__ U, const float* __restrict__ nmw,
                           const float* __restrict__ pm, const float* __restrict__ qs,
                           unsigned short* __restrict__ z1wbf, unsigned short* __restrict__ wcatbf,
                           unsigned short* __restrict__ nmbf, unsigned short* __restrict__ pmbf,
                           unsigned short* __restrict__ qbf) {
  int idx = blockIdx.x * 256 + threadIdx.x;
  if (idx < 262144) { z1wbf[idx] = f2bf(z1w[idx]); return; }
  idx -= 262144;
  if (idx < 131072) {
    int o = idx >> 8, k = idx & 255;
    wcatbf[idx] = f2bf(o < 256 ? Ur[o * 256 + k] : U[(o - 256) * 256 + k]);
    return;
  }
  idx -= 131072;
  if (idx < 196608) { nmbf[idx] = f2bf(nmw[idx]); return; }
  idx -= 196608;
  if (idx < 262144) { pmbf[idx] = f2bf(pm[idx]); return; }
  idx -= 262144;
  if (idx < 262144) { qbf[idx] = f2bf(qs[idx]); return; }
}

// ---------------------------------------------------------------------------
// Phase B: FWr[b,h] = facts[b]·Wr[h] + Wr_b[h] + Ur_b[h];  FW[b,h] = facts[b]·W[h] + W_b[h]
// ---------------------------------------------------------------------------
__global__ __launch_bounds__(256) void fact_proj(
    const float* __restrict__ facts, const float* __restrict__ Wr, const float* __restrict__ Wrb,
    const float* __restrict__ Urb, const float* __restrict__ Ww, const float* __restrict__ Wb,
    float* __restrict__ FWr, float* __restrict__ FW) {
  __shared__ float fl[4][HH];
  const int b0 = blockIdx.x * 4;
  const int tid = threadIdx.x;
#pragma unroll
  for (int r = 0; r < 4; ++r) fl[r][tid] = facts[(b0 + r) * HH + tid];
  __syncthreads();
  float ar[4] = {0.f, 0.f, 0.f, 0.f}, aw[4] = {0.f, 0.f, 0.f, 0.f};
  const float4* wr = (const float4*)(Wr + tid * HH);
  const float4* ww = (const float4*)(Ww + tid * HH);
  for (int d4 = 0; d4 < 64; ++d4) {
    float4 a = wr[d4], b = ww[d4];
#pragma unroll
    for (int r = 0; r < 4; ++r) {
      float4 f = *(const float4*)&fl[r][d4 * 4];  // LDS broadcast
      ar[r] += a.x * f.x + a.y * f.y + a.z * f.z + a.w * f.w;
      aw[r] += b.x * f.x + b.y * f.y + b.z * f.z + b.w * f.w;
    }
  }
  const float br = Wrb[tid] + Urb[tid], bw = Wb[tid];
#pragma unroll
  for (int r = 0; r < 4; ++r) {
    FWr[(b0 + r) * HH + tid] = ar[r] + br;
    FW[(b0 + r) * HH + tid] = aw[r] + bw;
  }
}

// ---------------------------------------------------------------------------
// Phase A: gate GEMM. (unchanged this round — counters next round)
// ---------------------------------------------------------------------------
__global__ __launch_bounds__(512, 2) void gate_gemm(
    const float* __restrict__ facts, const float* __restrict__ prevM,
    const float* __restrict__ questions, const unsigned short* __restrict__ z1wbf,
    const float* __restrict__ z1b, const float* __restrict__ z2w,
    const float* __restrict__ z2b, float* __restrict__ G) {
  __shared__ unsigned short A[128][136];
  __shared__ float Gpart[128][4];
  const int bi = blockIdx.x;
  const int n = bi >> 5, i0 = (bi & 31) * 2;
  const int tid = threadIdx.x;
  const int w = tid >> 6, l = tid & 63;
  const int rg = w >> 2, cg = w & 3;
  const int l15 = l & 15, q = l >> 4;
  const int hh2 = (tid & 15) * 2, jb = tid >> 4;

  const float* fn = facts + n * SS * HH;
  const float* qn = questions + (n * SS + i0) * HH;
  const float* mn = prevM + (n * SS + i0) * HH;

  const f32x4 zero4 = {0.f, 0.f, 0.f, 0.f};
  f32x4 acc[4][4];
#pragma unroll
  for (int a = 0; a < 4; ++a)
#pragma unroll
    for (int b = 0; b < 4; ++b) acc[a][b] = zero4;

  float2 fv0, fv1, qv0, qv1, mv0, mv1;
  auto prefetch = [&](int hc) {
    const int h = hc * 32 + hh2;
    fv0 = *(const float2*)(fn + jb * HH + h);
    fv1 = *(const float2*)(fn + (jb + 32) * HH + h);
    qv0 = *(const float2*)(qn + h);
    qv1 = *(const float2*)(qn + HH + h);
    mv0 = *(const float2*)(mn + h);
    mv1 = *(const float2*)(mn + HH + h);
  };
  prefetch(0);

  for (int hc = 0; hc < 8; ++hc) {
    short8 Bf[4][4];
    const unsigned short* bb = z1wbf + (cg * 64 + l15) * 1024 + hc * 32 + q * 8;
#pragma unroll
    for (int s = 0; s < 4; ++s)
#pragma unroll
      for (int nf = 0; nf < 4; ++nf)
        Bf[s][nf] = *(const short8*)(bb + (nf * 16) * 1024 + s * 256);

    {
      float2 fl2[2] = {fv0, fv1}, ql2[2] = {qv0, qv1}, ml2[2] = {mv0, mv1};
#pragma unroll
      for (int pl = 0; pl < 2; ++pl) {
        const int j = jb + pl * 32;
#pragma unroll
        for (int il = 0; il < 2; ++il) {
          const int row = il * 64 + j;
          const float fx = fl2[pl].x, fy = fl2[pl].y;
          const float qx = ql2[il].x, qy = ql2[il].y;
          const float mx = ml2[il].x, my = ml2[il].y;
          *(unsigned int*)&A[row][0 * 32 + hh2] = pk2(fx * qx, fy * qy);
          *(unsigned int*)&A[row][1 * 32 + hh2] = pk2(fx * mx, fy * my);
          *(unsigned int*)&A[row][2 * 32 + hh2] = pk2(fabsf(fx - qx), fabsf(fy - qy));
          *(unsigned int*)&A[row][3 * 32 + hh2] = pk2(fabsf(fx - mx), fabsf(fy - my));
        }
      }
    }
    if (hc < 7) prefetch(hc + 1);
    __syncthreads();

#pragma unroll
    for (int s = 0; s < 4; ++s) {
      short8 Af[4];
#pragma unroll
      for (int mf = 0; mf < 4; ++mf)
        Af[mf] = *(const short8*)&A[rg * 64 + mf * 16 + l15][s * 32 + q * 8];
#pragma unroll
      for (int mf = 0; mf < 4; ++mf)
#pragma unroll
        for (int nf = 0; nf < 4; ++nf)
          acc[mf][nf] = __builtin_amdgcn_mfma_f32_16x16x32_bf16(Af[mf], Bf[s][nf], acc[mf][nf], 0, 0, 0);
    }
    __syncthreads();
  }

  float psum[4][4];
#pragma unroll
  for (int mf = 0; mf < 4; ++mf)
#pragma unroll
    for (int v = 0; v < 4; ++v) psum[mf][v] = 0.f;

#pragma unroll
  for (int nf = 0; nf < 4; ++nf) {
    const int k = cg * 64 + nf * 16 + l15;
    const float zb = z1b[k], zw = z2w[k];
#pragma unroll
    for (int mf = 0; mf < 4; ++mf)
#pragma unroll
      for (int v = 0; v < 4; ++v) {
        const float x = acc[mf][nf][v] + zb;
        const float e = __expf(2.f * x);
        const float t = 1.f - 2.f / (e + 1.f);
        psum[mf][v] += zw * t;
      }
  }
#pragma unroll
  for (int d = 1; d < 16; d <<= 1)
#pragma unroll
    for (int mf = 0; mf < 4; ++mf)
#pragma unroll
      for (int v = 0; v < 4; ++v) psum[mf][v] += __shfl_xor(psum[mf][v], d, 64);
  if (l15 == 0) {
#pragma unroll
    for (int mf = 0; mf < 4; ++mf)
#pragma unroll
      for (int v = 0; v < 4; ++v)
        Gpart[rg * 64 + mf * 16 + q * 4 + v][cg] = psum[mf][v];
  }
  __syncthreads();
  if (tid < 128) {
    const float g = Gpart[tid][0] + Gpart[tid][1] + Gpart[tid][2] + Gpart[tid][3] + z2b[0];
    const int i = i0 + (tid >> 6), j = tid & 63;
    G[(n * SS + i) * SS + j] = g;
  }
}

// ---------------------------------------------------------------------------
// Phase A2: masked softmax over j. One wave per (n,i); lane = j.
// ---------------------------------------------------------------------------
__global__ void softmax_attn(const float* __restrict__ G, const int* __restrict__ doc_len,
                             float* __restrict__ attn) {
  const int gid = blockIdx.x * 256 + threadIdx.x;
  const int wid = gid >> 6, l = gid & 63;
  const int n = wid >> 6, i = wid & 63;
  const int dl = doc_len[n];
  const float g = G[(n * SS + i) * SS + l];
  const float x = (l < dl && g != 0.0f) ? g : -INFINITY;
  float mx = x;
#pragma unroll
  for (int d = 1; d < 64; d <<= 1) mx = fmaxf(mx, __shfl_xor(mx, d, 64));
  const float e = (x == -INFINITY) ? 0.f : __expf(x - mx);
  float s = e;
#pragma unroll
  for (int d = 1; d < 64; d <<= 1) s += __shfl_xor(s, d, 64);
  attn[(n * SS + i) * SS + l] = e / s;
}

// ---------------------------------------------------------------------------
// Phase C (RESTRUCTURED): GRU scan, 1 barrier/step, register-resident state.
// Block = 16 rows, 8 waves. Wave w owns output cols [32w, 32w+32) for BOTH
// Ur (r-gate) and U (u-term): Br/Bu fragments persistent in VGPRs (128 regs).
// Lane holds yr & yu for its (row, h) pairs -> GRU update fully in registers,
// Cf fp32 in regs (8/lane). Only bf16 A-fragment copy of C goes to LDS,
// double-buffered (stride 266 shorts = 133 words, 5 mod 32 -> 2-way max).
// __launch_bounds__(512,1): VGPR cap 256 so B-frags stay resident (fix for
// R1's VGPR=92 demotion under (512,2)'s 128-reg cap).
// ---------------------------------------------------------------------------
__global__ __launch_bounds__(512, 1) void gru_scan(
    const unsigned short* __restrict__ wcat, const float* __restrict__ FWr,
    const float* __restrict__ FW, const float* __restrict__ Ub,
    const float* __restrict__ attn, unsigned short* __restrict__ Cout) {
  __shared__ unsigned short Cbf[2][16 * 266];
  __shared__ float attn_s[16 * 65];  // stride 65: conflict-free gate reads

  const int bi = blockIdx.x, n = bi >> 2, i0 = (bi & 3) * 16;
  const int tid = threadIdx.x, w = tid >> 6, l = tid & 63;
  const int l15 = l & 15, q = l >> 4;
  const int h0 = w * 32 + l15;   // output col, nf=0
  const int h1 = h0 + 16;        // output col, nf=1

  // Persistent B-fragments: B[k=q*8+j][col=l15] = W[col][k]
  short8 Br0[8], Br1[8], Bu0[8], Bu1[8];
  {
    const unsigned short* b0 = wcat + h0 * 256 + q * 8;
#pragma unroll
    for (int kt = 0; kt < 8; ++kt) {
      Br0[kt] = *(const short8*)(b0 + kt * 32);
      Br1[kt] = *(const short8*)(b0 + 16 * 256 + kt * 32);
      Bu0[kt] = *(const short8*)(b0 + 256 * 256 + kt * 32);
      Bu1[kt] = *(const short8*)(b0 + 272 * 256 + kt * 32);
    }
  }
  const float ub0 = Ub[h0], ub1 = Ub[h1];

  for (int e = tid; e < 16 * 64; e += 512)
    attn_s[(e >> 6) * 65 + (e & 63)] = attn[(n * SS + i0 + (e >> 6)) * SS + (e & 63)];
  for (int e = tid; e < (16 * 266) / 2; e += 512) ((unsigned int*)Cbf[0])[e] = 0u;
  __syncthreads();

  float Cf0[4] = {0.f, 0.f, 0.f, 0.f}, Cf1[4] = {0.f, 0.f, 0.f, 0.f};

  const float* fwr_g = FWr + (n * SS) * HH;
  const float* fw_g  = FW + (n * SS) * HH;

  for (int t = 0; t < 64; ++t) {
    // prefetch per-step scalars (global, L2-resident; overlaps ds_read+MFMA)
    const float fwr0 = fwr_g[t * HH + h0], fwr1 = fwr_g[t * HH + h1];
    const float fw0  = fw_g[t * HH + h0],  fw1  = fw_g[t * HH + h1];

    // A fragments from current buffer
    const unsigned short* cb = Cbf[t & 1] + l15 * 266 + q * 8;
    short8 Af[8];
#pragma unroll
    for (int kt = 0; kt < 8; ++kt) Af[kt] = *(const short8*)(cb + kt * 32);

    f32x4 ar0 = {0.f, 0.f, 0.f, 0.f}, ar1 = ar0, au0 = ar0, au1 = ar0;
#pragma unroll
    for (int kt = 0; kt < 8; ++kt) {
      ar0 = __builtin_amdgcn_mfma_f32_16x16x32_bf16(Af[kt], Br0[kt], ar0, 0, 0, 0);
      ar1 = __builtin_amdgcn_mfma_f32_16x16x32_bf16(Af[kt], Br1[kt], ar1, 0, 0, 0);
      au0 = __builtin_amdgcn_mfma_f32_16x16x32_bf16(Af[kt], Bu0[kt], au0, 0, 0, 0);
      au1 = __builtin_amdgcn_mfma_f32_16x16x32_bf16(Af[kt], Bu1[kt], au1, 0, 0, 0);
    }

    // GRU update in registers; publish bf16 copy to next buffer
    unsigned short* cw = Cbf[(t + 1) & 1];
#pragma unroll
    for (int v = 0; v < 4; ++v) {
      const int row = q * 4 + v;
      const float g = attn_s[row * 65 + t];
      {
        const float r  = 1.f / (1.f + __expf(-(fwr0 + ar0[v])));
        const float x  = fw0 + r * (au0[v] + ub0);
        const float eh = __expf(2.f * x);
        const float ht = 1.f - 2.f / (eh + 1.f);
        const float cn = g * ht + (1.f - g) * Cf0[v];
        Cf0[v] = cn;
        cw[row * 266 + h0] = f2bf(cn);
      }
      {
        const float r  = 1.f / (1.f + __expf(-(fwr1 + ar1[v])));
        const float x  = fw1 + r * (au1[v] + ub1);
        const float eh = __expf(2.f * x);
        const float ht = 1.f - 2.f / (eh + 1.f);
        const float cn = g * ht + (1.f - g) * Cf1[v];
        Cf1[v] = cn;
        cw[row * 266 + h1] = f2bf(cn);
      }
    }
    __syncthreads();  // write(t+1) -> read(t+1); WAR safe via double buffer
  }

  // final C (bf16) for phase D, straight from registers
#pragma unroll
  for (int v = 0; v < 4; ++v) {
    const int row = i0 + q * 4 + v;
    Cout[(n * SS + row) * HH + h0] = f2bf(Cf0[v]);
    Cout[(n * SS + row) * HH + h1] = f2bf(Cf1[v]);
  }
}

// ---------------------------------------------------------------------------
// Phase D: next_mem = relu([prevM | C | questions] @ nm_w^T + nm_b)
// ---------------------------------------------------------------------------
__global__ __launch_bounds__(256) void next_mem_gemm(
    const unsigned short* __restrict__ pmbf, const unsigned short* __restrict__ cbf,
    const unsigned short* __restrict__ qbf, const unsigned short* __restrict__ nmbf,
    const float* __restrict__ nmb, float* __restrict__ out) {
  __shared__ unsigned short A[64][40];
  const int bi = blockIdx.x;
  const int rb = bi >> 2, cb = bi & 3;
  const int r0 = rb * 64, c0 = cb * 64;
  const int tid = threadIdx.x, w = tid >> 6, l = tid & 63;
  const int l15 = l & 15, q = l >> 4;

  f32x4 acc[4];
  const f32x4 z4 = {0.f, 0.f, 0.f, 0.f};
#pragma unroll
  for (int nf = 0; nf < 4; ++nf) acc[nf] = z4;

  for (int kt = 0; kt < 24; ++kt) {
    const int kg = kt * 32;
    const unsigned short* src =
        kg < 256 ? (pmbf + kg) : (kg < 512 ? (cbf + kg - 256) : (qbf + kg - 512));
    const int kk = (tid & 15) * 2;
#pragma unroll
    for (int ps = 0; ps < 4; ++ps) {
      const int row = ps * 16 + (tid >> 4);
      *(unsigned int*)&A[row][kk] = *(const unsigned int*)(src + (r0 + row) * HH + kk);
    }
    __syncthreads();
    short8 Bfr[4];
#pragma unroll
    for (int nf = 0; nf < 4; ++nf)
      Bfr[nf] = *(const short8*)(nmbf + (c0 + nf * 16 + l15) * 768 + kg + q * 8);
    const short8 Af = *(const short8*)&A[w * 16 + l15][q * 8];
#pragma unroll
    for (int nf = 0; nf < 4; ++nf)
      acc[nf] = __builtin_amdgcn_mfma_f32_16x16x32_bf16(Af, Bfr[nf], acc[nf], 0, 0, 0);
    __syncthreads();
  }
#pragma unroll
  for (int nf = 0; nf < 4; ++nf) {
    const int col = c0 + nf * 16 + l15;
    const float bv = nmb[col];
#pragma unroll
    for (int v = 0; v < 4; ++v) {
      const int grow = r0 + w * 16 + q * 4 + v;
      out[grow * HH + col] = fmaxf(acc[nf][v] + bv, 0.f);
    }
  }
}

// ---------------------------------------------------------------------------
extern "C" void kernel_launch(void* const* d_in, const int* in_sizes, int n_in,
                              void* d_out, int out_size, void* d_ws, size_t ws_size,
                              hipStream_t stream) {
  const float* facts     = (const float*)d_in[0];
  const float* prevM     = (const float*)d_in[1];
  const float* questions = (const float*)d_in[2];
  const int*   doc_len   = (const int*)d_in[3];
  const float* z1w = (const float*)d_in[4];
  const float* z1b = (const float*)d_in[5];
  const float* z2w = (const float*)d_in[6];
  const float* z2b = (const float*)d_in[7];
  const float* Wrw = (const float*)d_in[8];
  const float* Wrb = (const float*)d_in[9];
  const float* Urw = (const float*)d_in[10];
  const float* Urb = (const float*)d_in[11];
  const float* Ww  = (const float*)d_in[12];
  const float* Wb  = (const float*)d_in[13];
  const float* Uw  = (const float*)d_in[14];
  const float* Ub  = (const float*)d_in[15];
  const float* nmw = (const float*)d_in[16];
  const float* nmb = (const float*)d_in[17];

  char* ws = (char*)d_ws;
  unsigned short* z1wbf  = (unsigned short*)(ws + 0);        // 512 KB
  unsigned short* wcatbf = (unsigned short*)(ws + 524288);   // 256 KB
  unsigned short* nmbf   = (unsigned short*)(ws + 786432);   // 384 KB
  unsigned short* pmbf   = (unsigned short*)(ws + 1179648);  // 512 KB
  unsigned short* qbf    = (unsigned short*)(ws + 1703936);  // 512 KB
  float* G   = (float*)(ws + 2228224);                       // 256 KB
  float* FWr = (float*)(ws + 2490368);                       // 1 MB
  float* FW  = (float*)(ws + 3538944);                       // 1 MB
  unsigned short* cbf = (unsigned short*)(ws + 4587520);     // 512 KB

  float* out  = (float*)d_out;
  float* attn = out + NB * SS * HH;

  prolog_cvt<<<4352, 256, 0, stream>>>(z1w, Urw, Uw, nmw, prevM, questions,
                                       z1wbf, wcatbf, nmbf, pmbf, qbf);
  fact_proj<<<256, 256, 0, stream>>>(facts, Wrw, Wrb, Urb, Ww, Wb, FWr, FW);
  gate_gemm<<<512, 512, 0, stream>>>(facts, prevM, questions, z1wbf, z1b, z2w, z2b, G);
  softmax_attn<<<256, 256, 0, stream>>>(G, doc_len, attn);
  gru_scan<<<64, 512, 0, stream>>>(wcatbf, FWr, FW, Ub, attn, cbf);
  next_mem_gemm<<<64, 256, 0, stream>>>(pmbf, cbf, qbf, nmbf, nmb, out);
}

// Round 3
// 406.914 us; speedup vs baseline: 1.0329x; 1.0329x over previous
//
#include <hip/hip_runtime.h>
#include <hip/hip_bf16.h>
#include <math.h>

#define NB 16
#define SS 64
#define HH 256
#define FAA 256

using short8 = __attribute__((ext_vector_type(8))) short;
using f32x4  = __attribute__((ext_vector_type(4))) float;

__device__ __forceinline__ unsigned short f2bf(float f) {
  union { float f; unsigned int u; } x; x.f = f;
  unsigned int u = x.u;
  return (unsigned short)((u + 0x7FFFu + ((u >> 16) & 1u)) >> 16);  // RNE
}
__device__ __forceinline__ unsigned int pk2(float a, float b) {
  return (unsigned int)f2bf(a) | ((unsigned int)f2bf(b) << 16);
}

// ---------------------------------------------------------------------------
// Prolog: fp32 -> bf16 conversions.
// wcat storage row o holds TRUE weight row sr = (o&~31) | ((o&15)<<1) | ((o>>4)&1)
// (so that in gru_scan, lane (w,l15) tiles nf=0/1 produce ADJACENT true cols
//  h0 = w*32+2*l15, h1 = h0+1 -> packed b32 LDS writes, float2 bias loads).
// rows 0..255 = Ur, 256..511 = U.
// ---------------------------------------------------------------------------
__global__ void prolog_cvt(const float* __restrict__ z1w, const float* __restrict__ Ur,
                           const float* __restrict__ U, const float* __restrict__ nmw,
                           const float* __restrict__ pm, const float* __restrict__ qs,
                           unsigned short* __restrict__ z1wbf, unsigned short* __restrict__ wcatbf,
                           unsigned short* __restrict__ nmbf, unsigned short* __restrict__ pmbf,
                           unsigned short* __restrict__ qbf) {
  int idx = blockIdx.x * 256 + threadIdx.x;
  if (idx < 262144) { z1wbf[idx] = f2bf(z1w[idx]); return; }
  idx -= 262144;
  if (idx < 131072) {
    int o = idx >> 8, k = idx & 255;
    int sr = (o & ~31) | ((o & 15) << 1) | ((o >> 4) & 1);  // permuted source row
    wcatbf[idx] = f2bf(sr < 256 ? Ur[sr * 256 + k] : U[(sr - 256) * 256 + k]);
    return;
  }
  idx -= 131072;
  if (idx < 196608) { nmbf[idx] = f2bf(nmw[idx]); return; }
  idx -= 196608;
  if (idx < 262144) { pmbf[idx] = f2bf(pm[idx]); return; }
  idx -= 262144;
  if (idx < 262144) { qbf[idx] = f2bf(qs[idx]); return; }
}

// ---------------------------------------------------------------------------
// Phase B: FWr[b,h] = facts[b]·Wr[h] + Wr_b[h] + Ur_b[h];  FW[b,h] = facts[b]·W[h] + W_b[h]
// ---------------------------------------------------------------------------
__global__ __launch_bounds__(256) void fact_proj(
    const float* __restrict__ facts, const float* __restrict__ Wr, const float* __restrict__ Wrb,
    const float* __restrict__ Urb, const float* __restrict__ Ww, const float* __restrict__ Wb,
    float* __restrict__ FWr, float* __restrict__ FW) {
  __shared__ float fl[4][HH];
  const int b0 = blockIdx.x * 4;
  const int tid = threadIdx.x;
#pragma unroll
  for (int r = 0; r < 4; ++r) fl[r][tid] = facts[(b0 + r) * HH + tid];
  __syncthreads();
  float ar[4] = {0.f, 0.f, 0.f, 0.f}, aw[4] = {0.f, 0.f, 0.f, 0.f};
  const float4* wr = (const float4*)(Wr + tid * HH);
  const float4* ww = (const float4*)(Ww + tid * HH);
  for (int d4 = 0; d4 < 64; ++d4) {
    float4 a = wr[d4], b = ww[d4];
#pragma unroll
    for (int r = 0; r < 4; ++r) {
      float4 f = *(const float4*)&fl[r][d4 * 4];  // LDS broadcast
      ar[r] += a.x * f.x + a.y * f.y + a.z * f.z + a.w * f.w;
      aw[r] += b.x * f.x + b.y * f.y + b.z * f.z + b.w * f.w;
    }
  }
  const float br = Wrb[tid] + Urb[tid], bw = Wb[tid];
#pragma unroll
  for (int r = 0; r < 4; ++r) {
    FWr[(b0 + r) * HH + tid] = ar[r] + br;
    FW[(b0 + r) * HH + tid] = aw[r] + bw;
  }
}

// ---------------------------------------------------------------------------
// Phase A: gate GEMM. Restructured: Bf/Af loaded per-section s so peak VGPR
// pressure is acc(64)+Af(16)+Bf(16)+misc ~ 135 < 256 cap -> no scratch spills.
// ---------------------------------------------------------------------------
__global__ __launch_bounds__(512, 2) void gate_gemm(
    const float* __restrict__ facts, const float* __restrict__ prevM,
    const float* __restrict__ questions, const unsigned short* __restrict__ z1wbf,
    const float* __restrict__ z1b, const float* __restrict__ z2w,
    const float* __restrict__ z2b, float* __restrict__ G) {
  __shared__ unsigned short A[128][136];
  __shared__ float Gpart[128][4];
  const int bi = blockIdx.x;
  const int n = bi >> 5, i0 = (bi & 31) * 2;
  const int tid = threadIdx.x;
  const int w = tid >> 6, l = tid & 63;
  const int rg = w >> 2, cg = w & 3;
  const int l15 = l & 15, q = l >> 4;
  const int hh2 = (tid & 15) * 2, jb = tid >> 4;

  const float* fn = facts + n * SS * HH;
  const float* qn = questions + (n * SS + i0) * HH;
  const float* mn = prevM + (n * SS + i0) * HH;

  const f32x4 zero4 = {0.f, 0.f, 0.f, 0.f};
  f32x4 acc[4][4];
#pragma unroll
  for (int a = 0; a < 4; ++a)
#pragma unroll
    for (int b = 0; b < 4; ++b) acc[a][b] = zero4;

  float2 fv0, fv1, qv0, qv1, mv0, mv1;
  auto prefetch = [&](int hc) {
    const int h = hc * 32 + hh2;
    fv0 = *(const float2*)(fn + jb * HH + h);
    fv1 = *(const float2*)(fn + (jb + 32) * HH + h);
    qv0 = *(const float2*)(qn + h);
    qv1 = *(const float2*)(qn + HH + h);
    mv0 = *(const float2*)(mn + h);
    mv1 = *(const float2*)(mn + HH + h);
  };
  prefetch(0);

  for (int hc = 0; hc < 8; ++hc) {
    // build A-tile from prefetched registers
    {
      float2 fl2[2] = {fv0, fv1}, ql2[2] = {qv0, qv1}, ml2[2] = {mv0, mv1};
#pragma unroll
      for (int pl = 0; pl < 2; ++pl) {
        const int j = jb + pl * 32;
#pragma unroll
        for (int il = 0; il < 2; ++il) {
          const int row = il * 64 + j;
          const float fx = fl2[pl].x, fy = fl2[pl].y;
          const float qx = ql2[il].x, qy = ql2[il].y;
          const float mx = ml2[il].x, my = ml2[il].y;
          *(unsigned int*)&A[row][0 * 32 + hh2] = pk2(fx * qx, fy * qy);
          *(unsigned int*)&A[row][1 * 32 + hh2] = pk2(fx * mx, fy * my);
          *(unsigned int*)&A[row][2 * 32 + hh2] = pk2(fabsf(fx - qx), fabsf(fy - qy));
          *(unsigned int*)&A[row][3 * 32 + hh2] = pk2(fabsf(fx - mx), fabsf(fy - my));
        }
      }
    }
    if (hc < 7) prefetch(hc + 1);
    __syncthreads();

    const unsigned short* bb = z1wbf + (cg * 64 + l15) * 1024 + hc * 32 + q * 8;
#pragma unroll
    for (int s = 0; s < 4; ++s) {
      short8 Bf[4];
#pragma unroll
      for (int nf = 0; nf < 4; ++nf)
        Bf[nf] = *(const short8*)(bb + (nf * 16) * 1024 + s * 256);
      short8 Af[4];
#pragma unroll
      for (int mf = 0; mf < 4; ++mf)
        Af[mf] = *(const short8*)&A[rg * 64 + mf * 16 + l15][s * 32 + q * 8];
#pragma unroll
      for (int mf = 0; mf < 4; ++mf)
#pragma unroll
        for (int nf = 0; nf < 4; ++nf)
          acc[mf][nf] = __builtin_amdgcn_mfma_f32_16x16x32_bf16(Af[mf], Bf[nf], acc[mf][nf], 0, 0, 0);
    }
    __syncthreads();
  }

  float psum[4][4];
#pragma unroll
  for (int mf = 0; mf < 4; ++mf)
#pragma unroll
    for (int v = 0; v < 4; ++v) psum[mf][v] = 0.f;

#pragma unroll
  for (int nf = 0; nf < 4; ++nf) {
    const int k = cg * 64 + nf * 16 + l15;
    const float zb = z1b[k], zw = z2w[k];
#pragma unroll
    for (int mf = 0; mf < 4; ++mf)
#pragma unroll
      for (int v = 0; v < 4; ++v) {
        const float x = acc[mf][nf][v] + zb;
        const float e = __expf(2.f * x);
        const float t = 1.f - 2.f / (e + 1.f);
        psum[mf][v] += zw * t;
      }
  }
#pragma unroll
  for (int d = 1; d < 16; d <<= 1)
#pragma unroll
    for (int mf = 0; mf < 4; ++mf)
#pragma unroll
      for (int v = 0; v < 4; ++v) psum[mf][v] += __shfl_xor(psum[mf][v], d, 64);
  if (l15 == 0) {
#pragma unroll
    for (int mf = 0; mf < 4; ++mf)
#pragma unroll
      for (int v = 0; v < 4; ++v)
        Gpart[rg * 64 + mf * 16 + q * 4 + v][cg] = psum[mf][v];
  }
  __syncthreads();
  if (tid < 128) {
    const float g = Gpart[tid][0] + Gpart[tid][1] + Gpart[tid][2] + Gpart[tid][3] + z2b[0];
    const int i = i0 + (tid >> 6), j = tid & 63;
    G[(n * SS + i) * SS + j] = g;
  }
}

// ---------------------------------------------------------------------------
// Phase A2: masked softmax over j. One wave per (n,i); lane = j.
// ---------------------------------------------------------------------------
__global__ void softmax_attn(const float* __restrict__ G, const int* __restrict__ doc_len,
                             float* __restrict__ attn) {
  const int gid = blockIdx.x * 256 + threadIdx.x;
  const int wid = gid >> 6, l = gid & 63;
  const int n = wid >> 6, i = wid & 63;
  const int dl = doc_len[n];
  const float g = G[(n * SS + i) * SS + l];
  const float x = (l < dl && g != 0.0f) ? g : -INFINITY;
  float mx = x;
#pragma unroll
  for (int d = 1; d < 64; d <<= 1) mx = fmaxf(mx, __shfl_xor(mx, d, 64));
  const float e = (x == -INFINITY) ? 0.f : __expf(x - mx);
  float s = e;
#pragma unroll
  for (int d = 1; d < 64; d <<= 1) s += __shfl_xor(s, d, 64);
  attn[(n * SS + i) * SS + l] = e / s;
}

// ---------------------------------------------------------------------------
// Phase C: GRU scan, 1 barrier/step. B-fragments (128 VGPR) are PINNED in
// registers via an empty asm "+v" inside the loop (loop-carried dep -> the
// compiler cannot sink/re-load them; fixes R1/R2's VGPR=92/104 demotion).
// wcat is row-permuted so lane outputs (nf=0,1) are adjacent true cols ->
// packed b32 C-writes, float2 bias/FWr/FW loads. FWr/FW prefetched 1 step.
// ---------------------------------------------------------------------------
__global__ __launch_bounds__(512, 2) void gru_scan(
    const unsigned short* __restrict__ wcat, const float* __restrict__ FWr,
    const float* __restrict__ FW, const float* __restrict__ Ub,
    const float* __restrict__ attn, unsigned short* __restrict__ Cout) {
  __shared__ unsigned short Cbf[2][16 * 266];  // 133 words stride: conflict-free b128 reads
  __shared__ float attn_s[16 * 65];

  const int bi = blockIdx.x, n = bi >> 2, i0 = (bi & 3) * 16;
  const int tid = threadIdx.x, w = tid >> 6, l = tid & 63;
  const int l15 = l & 15, q = l >> 4;
  const int h0 = w * 32 + 2 * l15;  // true col of tile nf=0; nf=1 is h0+1

  // Persistent B-fragments (storage rows; permutation maps them to h0/h0+1)
  short8 Br0[8], Br1[8], Bu0[8], Bu1[8];
  {
    const unsigned short* b0 = wcat + (w * 32 + l15) * 256 + q * 8;
#pragma unroll
    for (int kt = 0; kt < 8; ++kt) {
      Br0[kt] = *(const short8*)(b0 + kt * 32);
      Br1[kt] = *(const short8*)(b0 + 16 * 256 + kt * 32);
      Bu0[kt] = *(const short8*)(b0 + 256 * 256 + kt * 32);
      Bu1[kt] = *(const short8*)(b0 + 272 * 256 + kt * 32);
    }
  }
  const float2 ub2 = *(const float2*)(Ub + h0);

  for (int e = tid; e < 16 * 64; e += 512)
    attn_s[(e >> 6) * 65 + (e & 63)] = attn[(n * SS + i0 + (e >> 6)) * SS + (e & 63)];
  for (int e = tid; e < (16 * 266) / 2; e += 512) ((unsigned int*)Cbf[0])[e] = 0u;
  __syncthreads();

  float Cf0[4] = {0.f, 0.f, 0.f, 0.f}, Cf1[4] = {0.f, 0.f, 0.f, 0.f};

  const float* fwr_g = FWr + (n * SS) * HH + h0;
  const float* fw_g  = FW + (n * SS) * HH + h0;
  float2 fwr2 = *(const float2*)(fwr_g);
  float2 fw2  = *(const float2*)(fw_g);

  for (int t = 0; t < 64; ++t) {
    // pin the 32 B-fragments in VGPRs (empty asm: 0 instructions, creates
    // loop-carried register dependency so they can't be re-fetched)
#pragma unroll
    for (int kt = 0; kt < 8; ++kt)
      asm("" : "+v"(Br0[kt]), "+v"(Br1[kt]), "+v"(Bu0[kt]), "+v"(Bu1[kt]));

    const unsigned short* cb = Cbf[t & 1] + l15 * 266 + q * 8;
    short8 Af[8];
#pragma unroll
    for (int kt = 0; kt < 8; ++kt) Af[kt] = *(const short8*)(cb + kt * 32);

    f32x4 ar0 = {0.f, 0.f, 0.f, 0.f}, ar1 = ar0, au0 = ar0, au1 = ar0;
#pragma unroll
    for (int kt = 0; kt < 8; ++kt) {
      ar0 = __builtin_amdgcn_mfma_f32_16x16x32_bf16(Af[kt], Br0[kt], ar0, 0, 0, 0);
      ar1 = __builtin_amdgcn_mfma_f32_16x16x32_bf16(Af[kt], Br1[kt], ar1, 0, 0, 0);
      au0 = __builtin_amdgcn_mfma_f32_16x16x32_bf16(Af[kt], Bu0[kt], au0, 0, 0, 0);
      au1 = __builtin_amdgcn_mfma_f32_16x16x32_bf16(Af[kt], Bu1[kt], au1, 0, 0, 0);
    }

    // prefetch next step's per-col scalars (wraps at t=63; value unused)
    const int tn = (t + 1) & 63;
    const float2 fwr2n = *(const float2*)(fwr_g + tn * HH);
    const float2 fw2n  = *(const float2*)(fw_g + tn * HH);

    unsigned short* cw = Cbf[(t + 1) & 1];
#pragma unroll
    for (int v = 0; v < 4; ++v) {
      const int row = q * 4 + v;
      const float g = attn_s[row * 65 + t];
      float cn0, cn1;
      {
        const float r  = 1.f / (1.f + __expf(-(fwr2.x + ar0[v])));
        const float x  = fw2.x + r * (au0[v] + ub2.x);
        const float eh = __expf(2.f * x);
        const float ht = 1.f - 2.f / (eh + 1.f);
        cn0 = g * ht + (1.f - g) * Cf0[v];
        Cf0[v] = cn0;
      }
      {
        const float r  = 1.f / (1.f + __expf(-(fwr2.y + ar1[v])));
        const float x  = fw2.y + r * (au1[v] + ub2.y);
        const float eh = __expf(2.f * x);
        const float ht = 1.f - 2.f / (eh + 1.f);
        cn1 = g * ht + (1.f - g) * Cf1[v];
        Cf1[v] = cn1;
      }
      *(unsigned int*)&cw[row * 266 + h0] = pk2(cn0, cn1);
    }
    fwr2 = fwr2n;
    fw2 = fw2n;
    __syncthreads();
  }

  // final C (bf16) for phase D, true col order
#pragma unroll
  for (int v = 0; v < 4; ++v) {
    const int row = i0 + q * 4 + v;
    *(unsigned int*)&Cout[(n * SS + row) * HH + h0] = pk2(Cf0[v], Cf1[v]);
  }
}

// ---------------------------------------------------------------------------
// Phase D: next_mem = relu([prevM | C | questions] @ nm_w^T + nm_b)
// ---------------------------------------------------------------------------
__global__ __launch_bounds__(256) void next_mem_gemm(
    const unsigned short* __restrict__ pmbf, const unsigned short* __restrict__ cbf,
    const unsigned short* __restrict__ qbf, const unsigned short* __restrict__ nmbf,
    const float* __restrict__ nmb, float* __restrict__ out) {
  __shared__ unsigned short A[64][40];
  const int bi = blockIdx.x;
  const int rb = bi >> 2, cb = bi & 3;
  const int r0 = rb * 64, c0 = cb * 64;
  const int tid = threadIdx.x, w = tid >> 6, l = tid & 63;
  const int l15 = l & 15, q = l >> 4;

  f32x4 acc[4];
  const f32x4 z4 = {0.f, 0.f, 0.f, 0.f};
#pragma unroll
  for (int nf = 0; nf < 4; ++nf) acc[nf] = z4;

  for (int kt = 0; kt < 24; ++kt) {
    const int kg = kt * 32;
    const unsigned short* src =
        kg < 256 ? (pmbf + kg) : (kg < 512 ? (cbf + kg - 256) : (qbf + kg - 512));
    const int kk = (tid & 15) * 2;
#pragma unroll
    for (int ps = 0; ps < 4; ++ps) {
      const int row = ps * 16 + (tid >> 4);
      *(unsigned int*)&A[row][kk] = *(const unsigned int*)(src + (r0 + row) * HH + kk);
    }
    __syncthreads();
    short8 Bfr[4];
#pragma unroll
    for (int nf = 0; nf < 4; ++nf)
      Bfr[nf] = *(const short8*)(nmbf + (c0 + nf * 16 + l15) * 768 + kg + q * 8);
    const short8 Af = *(const short8*)&A[w * 16 + l15][q * 8];
#pragma unroll
    for (int nf = 0; nf < 4; ++nf)
      acc[nf] = __builtin_amdgcn_mfma_f32_16x16x32_bf16(Af, Bfr[nf], acc[nf], 0, 0, 0);
    __syncthreads();
  }
#pragma unroll
  for (int nf = 0; nf < 4; ++nf) {
    const int col = c0 + nf * 16 + l15;
    const float bv = nmb[col];
#pragma unroll
    for (int v = 0; v < 4; ++v) {
      const int grow = r0 + w * 16 + q * 4 + v;
      out[grow * HH + col] = fmaxf(acc[nf][v] + bv, 0.f);
    }
  }
}

// ---------------------------------------------------------------------------
extern "C" void kernel_launch(void* const* d_in, const int* in_sizes, int n_in,
                              void* d_out, int out_size, void* d_ws, size_t ws_size,
                              hipStream_t stream) {
  const float* facts     = (const float*)d_in[0];
  const float* prevM     = (const float*)d_in[1];
  const float* questions = (const float*)d_in[2];
  const int*   doc_len   = (const int*)d_in[3];
  const float* z1w = (const float*)d_in[4];
  const float* z1b = (const float*)d_in[5];
  const float* z2w = (const float*)d_in[6];
  const float* z2b = (const float*)d_in[7];
  const float* Wrw = (const float*)d_in[8];
  const float* Wrb = (const float*)d_in[9];
  const float* Urw = (const float*)d_in[10];
  const float* Urb = (const float*)d_in[11];
  const float* Ww  = (const float*)d_in[12];
  const float* Wb  = (const float*)d_in[13];
  const float* Uw  = (const float*)d_in[14];
  const float* Ub  = (const float*)d_in[15];
  const float* nmw = (const float*)d_in[16];
  const float* nmb = (const float*)d_in[17];

  char* ws = (char*)d_ws;
  unsigned short* z1wbf  = (unsigned short*)(ws + 0);        // 512 KB
  unsigned short* wcatbf = (unsigned short*)(ws + 524288);   // 256 KB
  unsigned short* nmbf   = (unsigned short*)(ws + 786432);   // 384 KB
  unsigned short* pmbf   = (unsigned short*)(ws + 1179648);  // 512 KB
  unsigned short* qbf    = (unsigned short*)(ws + 1703936);  // 512 KB
  float* G   = (float*)(ws + 2228224);                       // 256 KB
  float* FWr = (float*)(ws + 2490368);                       // 1 MB
  float* FW  = (float*)(ws + 3538944);                       // 1 MB
  unsigned short* cbf = (unsigned short*)(ws + 4587520);     // 512 KB

  float* out  = (float*)d_out;
  float* attn = out + NB * SS * HH;

  prolog_cvt<<<4352, 256, 0, stream>>>(z1w, Urw, Uw, nmw, prevM, questions,
                                       z1wbf, wcatbf, nmbf, pmbf, qbf);
  fact_proj<<<256, 256, 0, stream>>>(facts, Wrw, Wrb, Urb, Ww, Wb, FWr, FW);
  gate_gemm<<<512, 512, 0, stream>>>(facts, prevM, questions, z1wbf, z1b, z2w, z2b, G);
  softmax_attn<<<256, 256, 0, stream>>>(G, doc_len, attn);
  gru_scan<<<64, 512, 0, stream>>>(wcatbf, FWr, FW, Ub, attn, cbf);
  next_mem_gemm<<<64, 256, 0, stream>>>(pmbf, cbf, qbf, nmbf, nmb, out);
}

// Round 4
// 391.044 us; speedup vs baseline: 1.0748x; 1.0406x over previous
//
#include <hip/hip_runtime.h>
#include <hip/hip_bf16.h>
#include <math.h>

#define NB 16
#define SS 64
#define HH 256
#define FAA 256

using short8 = __attribute__((ext_vector_type(8))) short;
using f32x4  = __attribute__((ext_vector_type(4))) float;

__device__ __forceinline__ unsigned short f2bf(float f) {
  union { float f; unsigned int u; } x; x.f = f;
  unsigned int u = x.u;
  return (unsigned short)((u + 0x7FFFu + ((u >> 16) & 1u)) >> 16);  // RNE
}
__device__ __forceinline__ unsigned int pk2(float a, float b) {
  return (unsigned int)f2bf(a) | ((unsigned int)f2bf(b) << 16);
}

// MFMA with B pinned in AGPRs ("a" constraint): forces the 32 loop-invariant
// B-fragments of gru_scan into the AGPR class, which the VGPR pressure
// heuristics cannot demote to per-iteration L2 reloads (R1-R3 failure mode:
// VGPR_Count stuck at 92-104, ~4700 cyc/step of B re-fetch through L2).
#define MFMA_BA(acc, a, b) \
  asm("v_mfma_f32_16x16x32_bf16 %0, %1, %2, %0" : "+v"(acc) : "v"(a), "a"(b))

// ---------------------------------------------------------------------------
// Prolog: fp32 -> bf16 conversions.
// wcat storage row o holds TRUE weight row sr = (o&~31) | ((o&15)<<1) | ((o>>4)&1)
// rows 0..255 = Ur, 256..511 = U.
// ---------------------------------------------------------------------------
__global__ void prolog_cvt(const float* __restrict__ z1w, const float* __restrict__ Ur,
                           const float* __restrict__ U, const float* __restrict__ nmw,
                           const float* __restrict__ pm, const float* __restrict__ qs,
                           unsigned short* __restrict__ z1wbf, unsigned short* __restrict__ wcatbf,
                           unsigned short* __restrict__ nmbf, unsigned short* __restrict__ pmbf,
                           unsigned short* __restrict__ qbf) {
  int idx = blockIdx.x * 256 + threadIdx.x;
  if (idx < 262144) { z1wbf[idx] = f2bf(z1w[idx]); return; }
  idx -= 262144;
  if (idx < 131072) {
    int o = idx >> 8, k = idx & 255;
    int sr = (o & ~31) | ((o & 15) << 1) | ((o >> 4) & 1);  // permuted source row
    wcatbf[idx] = f2bf(sr < 256 ? Ur[sr * 256 + k] : U[(sr - 256) * 256 + k]);
    return;
  }
  idx -= 131072;
  if (idx < 196608) { nmbf[idx] = f2bf(nmw[idx]); return; }
  idx -= 196608;
  if (idx < 262144) { pmbf[idx] = f2bf(pm[idx]); return; }
  idx -= 262144;
  if (idx < 262144) { qbf[idx] = f2bf(qs[idx]); return; }
}

// ---------------------------------------------------------------------------
// Phase B: FWr[b,h] = facts[b]·Wr[h] + Wr_b[h] + Ur_b[h];  FW[b,h] = facts[b]·W[h] + W_b[h]
// ---------------------------------------------------------------------------
__global__ __launch_bounds__(256) void fact_proj(
    const float* __restrict__ facts, const float* __restrict__ Wr, const float* __restrict__ Wrb,
    const float* __restrict__ Urb, const float* __restrict__ Ww, const float* __restrict__ Wb,
    float* __restrict__ FWr, float* __restrict__ FW) {
  __shared__ float fl[4][HH];
  const int b0 = blockIdx.x * 4;
  const int tid = threadIdx.x;
#pragma unroll
  for (int r = 0; r < 4; ++r) fl[r][tid] = facts[(b0 + r) * HH + tid];
  __syncthreads();
  float ar[4] = {0.f, 0.f, 0.f, 0.f}, aw[4] = {0.f, 0.f, 0.f, 0.f};
  const float4* wr = (const float4*)(Wr + tid * HH);
  const float4* ww = (const float4*)(Ww + tid * HH);
  for (int d4 = 0; d4 < 64; ++d4) {
    float4 a = wr[d4], b = ww[d4];
#pragma unroll
    for (int r = 0; r < 4; ++r) {
      float4 f = *(const float4*)&fl[r][d4 * 4];  // LDS broadcast
      ar[r] += a.x * f.x + a.y * f.y + a.z * f.z + a.w * f.w;
      aw[r] += b.x * f.x + b.y * f.y + b.z * f.z + b.w * f.w;
    }
  }
  const float br = Wrb[tid] + Urb[tid], bw = Wb[tid];
#pragma unroll
  for (int r = 0; r < 4; ++r) {
    FWr[(b0 + r) * HH + tid] = ar[r] + br;
    FW[(b0 + r) * HH + tid] = aw[r] + bw;
  }
}

// ---------------------------------------------------------------------------
// Phase A: gate GEMM. (unchanged; counters expected next round)
// ---------------------------------------------------------------------------
__global__ __launch_bounds__(512, 2) void gate_gemm(
    const float* __restrict__ facts, const float* __restrict__ prevM,
    const float* __restrict__ questions, const unsigned short* __restrict__ z1wbf,
    const float* __restrict__ z1b, const float* __restrict__ z2w,
    const float* __restrict__ z2b, float* __restrict__ G) {
  __shared__ unsigned short A[128][136];
  __shared__ float Gpart[128][4];
  const int bi = blockIdx.x;
  const int n = bi >> 5, i0 = (bi & 31) * 2;
  const int tid = threadIdx.x;
  const int w = tid >> 6, l = tid & 63;
  const int rg = w >> 2, cg = w & 3;
  const int l15 = l & 15, q = l >> 4;
  const int hh2 = (tid & 15) * 2, jb = tid >> 4;

  const float* fn = facts + n * SS * HH;
  const float* qn = questions + (n * SS + i0) * HH;
  const float* mn = prevM + (n * SS + i0) * HH;

  const f32x4 zero4 = {0.f, 0.f, 0.f, 0.f};
  f32x4 acc[4][4];
#pragma unroll
  for (int a = 0; a < 4; ++a)
#pragma unroll
    for (int b = 0; b < 4; ++b) acc[a][b] = zero4;

  float2 fv0, fv1, qv0, qv1, mv0, mv1;
  auto prefetch = [&](int hc) {
    const int h = hc * 32 + hh2;
    fv0 = *(const float2*)(fn + jb * HH + h);
    fv1 = *(const float2*)(fn + (jb + 32) * HH + h);
    qv0 = *(const float2*)(qn + h);
    qv1 = *(const float2*)(qn + HH + h);
    mv0 = *(const float2*)(mn + h);
    mv1 = *(const float2*)(mn + HH + h);
  };
  prefetch(0);

  for (int hc = 0; hc < 8; ++hc) {
    {
      float2 fl2[2] = {fv0, fv1}, ql2[2] = {qv0, qv1}, ml2[2] = {mv0, mv1};
#pragma unroll
      for (int pl = 0; pl < 2; ++pl) {
        const int j = jb + pl * 32;
#pragma unroll
        for (int il = 0; il < 2; ++il) {
          const int row = il * 64 + j;
          const float fx = fl2[pl].x, fy = fl2[pl].y;
          const float qx = ql2[il].x, qy = ql2[il].y;
          const float mx = ml2[il].x, my = ml2[il].y;
          *(unsigned int*)&A[row][0 * 32 + hh2] = pk2(fx * qx, fy * qy);
          *(unsigned int*)&A[row][1 * 32 + hh2] = pk2(fx * mx, fy * my);
          *(unsigned int*)&A[row][2 * 32 + hh2] = pk2(fabsf(fx - qx), fabsf(fy - qy));
          *(unsigned int*)&A[row][3 * 32 + hh2] = pk2(fabsf(fx - mx), fabsf(fy - my));
        }
      }
    }
    if (hc < 7) prefetch(hc + 1);
    __syncthreads();

    const unsigned short* bb = z1wbf + (cg * 64 + l15) * 1024 + hc * 32 + q * 8;
#pragma unroll
    for (int s = 0; s < 4; ++s) {
      short8 Bf[4];
#pragma unroll
      for (int nf = 0; nf < 4; ++nf)
        Bf[nf] = *(const short8*)(bb + (nf * 16) * 1024 + s * 256);
      short8 Af[4];
#pragma unroll
      for (int mf = 0; mf < 4; ++mf)
        Af[mf] = *(const short8*)&A[rg * 64 + mf * 16 + l15][s * 32 + q * 8];
#pragma unroll
      for (int mf = 0; mf < 4; ++mf)
#pragma unroll
        for (int nf = 0; nf < 4; ++nf)
          acc[mf][nf] = __builtin_amdgcn_mfma_f32_16x16x32_bf16(Af[mf], Bf[nf], acc[mf][nf], 0, 0, 0);
    }
    __syncthreads();
  }

  float psum[4][4];
#pragma unroll
  for (int mf = 0; mf < 4; ++mf)
#pragma unroll
    for (int v = 0; v < 4; ++v) psum[mf][v] = 0.f;

#pragma unroll
  for (int nf = 0; nf < 4; ++nf) {
    const int k = cg * 64 + nf * 16 + l15;
    const float zb = z1b[k], zw = z2w[k];
#pragma unroll
    for (int mf = 0; mf < 4; ++mf)
#pragma unroll
      for (int v = 0; v < 4; ++v) {
        const float x = acc[mf][nf][v] + zb;
        const float e = __expf(2.f * x);
        const float t = 1.f - 2.f / (e + 1.f);
        psum[mf][v] += zw * t;
      }
  }
#pragma unroll
  for (int d = 1; d < 16; d <<= 1)
#pragma unroll
    for (int mf = 0; mf < 4; ++mf)
#pragma unroll
      for (int v = 0; v < 4; ++v) psum[mf][v] += __shfl_xor(psum[mf][v], d, 64);
  if (l15 == 0) {
#pragma unroll
    for (int mf = 0; mf < 4; ++mf)
#pragma unroll
      for (int v = 0; v < 4; ++v)
        Gpart[rg * 64 + mf * 16 + q * 4 + v][cg] = psum[mf][v];
  }
  __syncthreads();
  if (tid < 128) {
    const float g = Gpart[tid][0] + Gpart[tid][1] + Gpart[tid][2] + Gpart[tid][3] + z2b[0];
    const int i = i0 + (tid >> 6), j = tid & 63;
    G[(n * SS + i) * SS + j] = g;
  }
}

// ---------------------------------------------------------------------------
// Phase A2: masked softmax over j. One wave per (n,i); lane = j.
// ---------------------------------------------------------------------------
__global__ void softmax_attn(const float* __restrict__ G, const int* __restrict__ doc_len,
                             float* __restrict__ attn) {
  const int gid = blockIdx.x * 256 + threadIdx.x;
  const int wid = gid >> 6, l = gid & 63;
  const int n = wid >> 6, i = wid & 63;
  const int dl = doc_len[n];
  const float g = G[(n * SS + i) * SS + l];
  const float x = (l < dl && g != 0.0f) ? g : -INFINITY;
  float mx = x;
#pragma unroll
  for (int d = 1; d < 64; d <<= 1) mx = fmaxf(mx, __shfl_xor(mx, d, 64));
  const float e = (x == -INFINITY) ? 0.f : __expf(x - mx);
  float s = e;
#pragma unroll
  for (int d = 1; d < 64; d <<= 1) s += __shfl_xor(s, d, 64);
  attn[(n * SS + i) * SS + l] = e / s;
}

// ---------------------------------------------------------------------------
// Phase C: GRU scan, 1 barrier/step. B-fragments live in AGPRs via "a"-
// constrained inline-asm MFMA (see MFMA_BA). FWr/FW prefetch issued at TOP of
// the body so the structural vmcnt(0) drain before s_barrier is covered by
// ~1000+ cycles of LDS reads + MFMAs. Explicit s_nop guards around asm MFMAs
// (compiler's hazard recognizer can't see into inline asm).
// ---------------------------------------------------------------------------
__global__ __launch_bounds__(512, 2) void gru_scan(
    const unsigned short* __restrict__ wcat, const float* __restrict__ FWr,
    const float* __restrict__ FW, const float* __restrict__ Ub,
    const float* __restrict__ attn, unsigned short* __restrict__ Cout) {
  __shared__ unsigned short Cbf[2][16 * 266];  // 133-word stride: conflict-free b128 reads
  __shared__ float attn_s[16 * 65];

  const int bi = blockIdx.x, n = bi >> 2, i0 = (bi & 3) * 16;
  const int tid = threadIdx.x, w = tid >> 6, l = tid & 63;
  const int l15 = l & 15, q = l >> 4;
  const int h0 = w * 32 + 2 * l15;  // true col of tile nf=0; nf=1 is h0+1

  // B-fragments (loaded once; held in AGPRs across the t-loop by MFMA_BA's
  // "a" constraint)
  short8 Br0[8], Br1[8], Bu0[8], Bu1[8];
  {
    const unsigned short* b0 = wcat + (w * 32 + l15) * 256 + q * 8;
#pragma unroll
    for (int kt = 0; kt < 8; ++kt) {
      Br0[kt] = *(const short8*)(b0 + kt * 32);
      Br1[kt] = *(const short8*)(b0 + 16 * 256 + kt * 32);
      Bu0[kt] = *(const short8*)(b0 + 256 * 256 + kt * 32);
      Bu1[kt] = *(const short8*)(b0 + 272 * 256 + kt * 32);
    }
  }
  const float2 ub2 = *(const float2*)(Ub + h0);

  for (int e = tid; e < 16 * 64; e += 512)
    attn_s[(e >> 6) * 65 + (e & 63)] = attn[(n * SS + i0 + (e >> 6)) * SS + (e & 63)];
  for (int e = tid; e < (16 * 266) / 2; e += 512) ((unsigned int*)Cbf[0])[e] = 0u;
  __syncthreads();

  float Cf0[4] = {0.f, 0.f, 0.f, 0.f}, Cf1[4] = {0.f, 0.f, 0.f, 0.f};

  const float* fwr_g = FWr + (n * SS) * HH + h0;
  const float* fw_g  = FW + (n * SS) * HH + h0;
  float2 fwr2 = *(const float2*)(fwr_g);
  float2 fw2  = *(const float2*)(fw_g);

  for (int t = 0; t < 64; ++t) {
    // prefetch next step's per-col scalars EARLY (drained at the barrier;
    // issuing here gives ~1000+ cyc of latency cover). Wraps at t=63 (unused).
    const int tn = (t + 1) & 63;
    const float2 fwr2n = *(const float2*)(fwr_g + tn * HH);
    const float2 fw2n  = *(const float2*)(fw_g + tn * HH);

    const unsigned short* cb = Cbf[t & 1] + l15 * 266 + q * 8;
    short8 Af[8];
#pragma unroll
    for (int kt = 0; kt < 8; ++kt) Af[kt] = *(const short8*)(cb + kt * 32);

    f32x4 ar0 = {0.f, 0.f, 0.f, 0.f}, ar1 = ar0, au0 = ar0, au1 = ar0;
    // >=2-cycle gap between acc zero-init (VALU writes) and first MFMA read
    asm("s_nop 1" : "+v"(ar0), "+v"(ar1), "+v"(au0), "+v"(au1));
#pragma unroll
    for (int kt = 0; kt < 8; ++kt) {
      MFMA_BA(ar0, Af[kt], Br0[kt]);
      MFMA_BA(ar1, Af[kt], Br1[kt]);
      MFMA_BA(au0, Af[kt], Bu0[kt]);
      MFMA_BA(au1, Af[kt], Bu1[kt]);
    }
    // MFMA dest -> VALU read hazard guard (ordered via operand dataflow)
    asm("s_nop 7\n\ts_nop 7" : "+v"(ar0), "+v"(ar1), "+v"(au0), "+v"(au1));

    unsigned short* cw = Cbf[(t + 1) & 1];
#pragma unroll
    for (int v = 0; v < 4; ++v) {
      const int row = q * 4 + v;
      const float g = attn_s[row * 65 + t];
      float cn0, cn1;
      {
        const float r  = 1.f / (1.f + __expf(-(fwr2.x + ar0[v])));
        const float x  = fw2.x + r * (au0[v] + ub2.x);
        const float eh = __expf(2.f * x);
        const float ht = 1.f - 2.f / (eh + 1.f);
        cn0 = g * ht + (1.f - g) * Cf0[v];
        Cf0[v] = cn0;
      }
      {
        const float r  = 1.f / (1.f + __expf(-(fwr2.y + ar1[v])));
        const float x  = fw2.y + r * (au1[v] + ub2.y);
        const float eh = __expf(2.f * x);
        const float ht = 1.f - 2.f / (eh + 1.f);
        cn1 = g * ht + (1.f - g) * Cf1[v];
        Cf1[v] = cn1;
      }
      *(unsigned int*)&cw[row * 266 + h0] = pk2(cn0, cn1);
    }
    fwr2 = fwr2n;
    fw2 = fw2n;
    __syncthreads();
  }

  // final C (bf16) for phase D, true col order
#pragma unroll
  for (int v = 0; v < 4; ++v) {
    const int row = i0 + q * 4 + v;
    *(unsigned int*)&Cout[(n * SS + row) * HH + h0] = pk2(Cf0[v], Cf1[v]);
  }
}

// ---------------------------------------------------------------------------
// Phase D: next_mem = relu([prevM | C | questions] @ nm_w^T + nm_b)
// ---------------------------------------------------------------------------
__global__ __launch_bounds__(256) void next_mem_gemm(
    const unsigned short* __restrict__ pmbf, const unsigned short* __restrict__ cbf,
    const unsigned short* __restrict__ qbf, const unsigned short* __restrict__ nmbf,
    const float* __restrict__ nmb, float* __restrict__ out) {
  __shared__ unsigned short A[64][40];
  const int bi = blockIdx.x;
  const int rb = bi >> 2, cb = bi & 3;
  const int r0 = rb * 64, c0 = cb * 64;
  const int tid = threadIdx.x, w = tid >> 6, l = tid & 63;
  const int l15 = l & 15, q = l >> 4;

  f32x4 acc[4];
  const f32x4 z4 = {0.f, 0.f, 0.f, 0.f};
#pragma unroll
  for (int nf = 0; nf < 4; ++nf) acc[nf] = z4;

  for (int kt = 0; kt < 24; ++kt) {
    const int kg = kt * 32;
    const unsigned short* src =
        kg < 256 ? (pmbf + kg) : (kg < 512 ? (cbf + kg - 256) : (qbf + kg - 512));
    const int kk = (tid & 15) * 2;
#pragma unroll
    for (int ps = 0; ps < 4; ++ps) {
      const int row = ps * 16 + (tid >> 4);
      *(unsigned int*)&A[row][kk] = *(const unsigned int*)(src + (r0 + row) * HH + kk);
    }
    __syncthreads();
    short8 Bfr[4];
#pragma unroll
    for (int nf = 0; nf < 4; ++nf)
      Bfr[nf] = *(const short8*)(nmbf + (c0 + nf * 16 + l15) * 768 + kg + q * 8);
    const short8 Af = *(const short8*)&A[w * 16 + l15][q * 8];
#pragma unroll
    for (int nf = 0; nf < 4; ++nf)
      acc[nf] = __builtin_amdgcn_mfma_f32_16x16x32_bf16(Af, Bfr[nf], acc[nf], 0, 0, 0);
    __syncthreads();
  }
#pragma unroll
  for (int nf = 0; nf < 4; ++nf) {
    const int col = c0 + nf * 16 + l15;
    const float bv = nmb[col];
#pragma unroll
    for (int v = 0; v < 4; ++v) {
      const int grow = r0 + w * 16 + q * 4 + v;
      out[grow * HH + col] = fmaxf(acc[nf][v] + bv, 0.f);
    }
  }
}

// ---------------------------------------------------------------------------
extern "C" void kernel_launch(void* const* d_in, const int* in_sizes, int n_in,
                              void* d_out, int out_size, void* d_ws, size_t ws_size,
                              hipStream_t stream) {
  const float* facts     = (const float*)d_in[0];
  const float* prevM     = (const float*)d_in[1];
  const float* questions = (const float*)d_in[2];
  const int*   doc_len   = (const int*)d_in[3];
  const float* z1w = (const float*)d_in[4];
  const float* z1b = (const float*)d_in[5];
  const float* z2w = (const float*)d_in[6];
  const float* z2b = (const float*)d_in[7];
  const float* Wrw = (const float*)d_in[8];
  const float* Wrb = (const float*)d_in[9];
  const float* Urw = (const float*)d_in[10];
  const float* Urb = (const float*)d_in[11];
  const float* Ww  = (const float*)d_in[12];
  const float* Wb  = (const float*)d_in[13];
  const float* Uw  = (const float*)d_in[14];
  const float* Ub  = (const float*)d_in[15];
  const float* nmw = (const float*)d_in[16];
  const float* nmb = (const float*)d_in[17];

  char* ws = (char*)d_ws;
  unsigned short* z1wbf  = (unsigned short*)(ws + 0);        // 512 KB
  unsigned short* wcatbf = (unsigned short*)(ws + 524288);   // 256 KB
  unsigned short* nmbf   = (unsigned short*)(ws + 786432);   // 384 KB
  unsigned short* pmbf   = (unsigned short*)(ws + 1179648);  // 512 KB
  unsigned short* qbf    = (unsigned short*)(ws + 1703936);  // 512 KB
  float* G   = (float*)(ws + 2228224);                       // 256 KB
  float* FWr = (float*)(ws + 2490368);                       // 1 MB
  float* FW  = (float*)(ws + 3538944);                       // 1 MB
  unsigned short* cbf = (unsigned short*)(ws + 4587520);     // 512 KB

  float* out  = (float*)d_out;
  float* attn = out + NB * SS * HH;

  prolog_cvt<<<4352, 256, 0, stream>>>(z1w, Urw, Uw, nmw, prevM, questions,
                                       z1wbf, wcatbf, nmbf, pmbf, qbf);
  fact_proj<<<256, 256, 0, stream>>>(facts, Wrw, Wrb, Urb, Ww, Wb, FWr, FW);
  gate_gemm<<<512, 512, 0, stream>>>(facts, prevM, questions, z1wbf, z1b, z2w, z2b, G);
  softmax_attn<<<256, 256, 0, stream>>>(G, doc_len, attn);
  gru_scan<<<64, 512, 0, stream>>>(wcatbf, FWr, FW, Ub, attn, cbf);
  next_mem_gemm<<<64, 256, 0, stream>>>(pmbf, cbf, qbf, nmbf, nmb, out);
}

// Round 5
// 390.126 us; speedup vs baseline: 1.0774x; 1.0024x over previous
//
#include <hip/hip_runtime.h>
#include <hip/hip_bf16.h>
#include <math.h>

#define NB 16
#define SS 64
#define HH 256
#define FAA 256

using short8 = __attribute__((ext_vector_type(8))) short;
using f32x4  = __attribute__((ext_vector_type(4))) float;

__device__ __forceinline__ unsigned short f2bf(float f) {
  union { float f; unsigned int u; } x; x.f = f;
  unsigned int u = x.u;
  return (unsigned short)((u + 0x7FFFu + ((u >> 16) & 1u)) >> 16);  // RNE
}
__device__ __forceinline__ unsigned int pk2(float a, float b) {
  return (unsigned int)f2bf(a) | ((unsigned int)f2bf(b) << 16);
}

// MFMA reading B from the AGPR class.
#define MFMA_BA(acc, a, b) \
  asm("v_mfma_f32_16x16x32_bf16 %0, %1, %2, %0" : "+v"(acc) : "v"(a), "a"(b))

// ---------------------------------------------------------------------------
// Prolog: fp32 -> bf16 conversions.
// wcat storage row o holds TRUE weight row sr = (o&~31) | ((o&15)<<1) | ((o>>4)&1)
// rows 0..255 = Ur, 256..511 = U.
// ---------------------------------------------------------------------------
__global__ void prolog_cvt(const float* __restrict__ z1w, const float* __restrict__ Ur,
                           const float* __restrict__ U, const float* __restrict__ nmw,
                           const float* __restrict__ pm, const float* __restrict__ qs,
                           unsigned short* __restrict__ z1wbf, unsigned short* __restrict__ wcatbf,
                           unsigned short* __restrict__ nmbf, unsigned short* __restrict__ pmbf,
                           unsigned short* __restrict__ qbf) {
  int idx = blockIdx.x * 256 + threadIdx.x;
  if (idx < 262144) { z1wbf[idx] = f2bf(z1w[idx]); return; }
  idx -= 262144;
  if (idx < 131072) {
    int o = idx >> 8, k = idx & 255;
    int sr = (o & ~31) | ((o & 15) << 1) | ((o >> 4) & 1);  // permuted source row
    wcatbf[idx] = f2bf(sr < 256 ? Ur[sr * 256 + k] : U[(sr - 256) * 256 + k]);
    return;
  }
  idx -= 131072;
  if (idx < 196608) { nmbf[idx] = f2bf(nmw[idx]); return; }
  idx -= 196608;
  if (idx < 262144) { pmbf[idx] = f2bf(pm[idx]); return; }
  idx -= 262144;
  if (idx < 262144) { qbf[idx] = f2bf(qs[idx]); return; }
}

// ---------------------------------------------------------------------------
// Phase B: FWr[b,h] = facts[b]·Wr[h] + Wr_b[h] + Ur_b[h];  FW[b,h] = facts[b]·W[h] + W_b[h]
// ---------------------------------------------------------------------------
__global__ __launch_bounds__(256) void fact_proj(
    const float* __restrict__ facts, const float* __restrict__ Wr, const float* __restrict__ Wrb,
    const float* __restrict__ Urb, const float* __restrict__ Ww, const float* __restrict__ Wb,
    float* __restrict__ FWr, float* __restrict__ FW) {
  __shared__ float fl[4][HH];
  const int b0 = blockIdx.x * 4;
  const int tid = threadIdx.x;
#pragma unroll
  for (int r = 0; r < 4; ++r) fl[r][tid] = facts[(b0 + r) * HH + tid];
  __syncthreads();
  float ar[4] = {0.f, 0.f, 0.f, 0.f}, aw[4] = {0.f, 0.f, 0.f, 0.f};
  const float4* wr = (const float4*)(Wr + tid * HH);
  const float4* ww = (const float4*)(Ww + tid * HH);
  for (int d4 = 0; d4 < 64; ++d4) {
    float4 a = wr[d4], b = ww[d4];
#pragma unroll
    for (int r = 0; r < 4; ++r) {
      float4 f = *(const float4*)&fl[r][d4 * 4];  // LDS broadcast
      ar[r] += a.x * f.x + a.y * f.y + a.z * f.z + a.w * f.w;
      aw[r] += b.x * f.x + b.y * f.y + b.z * f.z + b.w * f.w;
    }
  }
  const float br = Wrb[tid] + Urb[tid], bw = Wb[tid];
#pragma unroll
  for (int r = 0; r < 4; ++r) {
    FWr[(b0 + r) * HH + tid] = ar[r] + br;
    FW[(b0 + r) * HH + tid] = aw[r] + bw;
  }
}

// ---------------------------------------------------------------------------
// Phase A: gate GEMM. (unchanged)
// ---------------------------------------------------------------------------
__global__ __launch_bounds__(512, 2) void gate_gemm(
    const float* __restrict__ facts, const float* __restrict__ prevM,
    const float* __restrict__ questions, const unsigned short* __restrict__ z1wbf,
    const float* __restrict__ z1b, const float* __restrict__ z2w,
    const float* __restrict__ z2b, float* __restrict__ G) {
  __shared__ unsigned short A[128][136];
  __shared__ float Gpart[128][4];
  const int bi = blockIdx.x;
  const int n = bi >> 5, i0 = (bi & 31) * 2;
  const int tid = threadIdx.x;
  const int w = tid >> 6, l = tid & 63;
  const int rg = w >> 2, cg = w & 3;
  const int l15 = l & 15, q = l >> 4;
  const int hh2 = (tid & 15) * 2, jb = tid >> 4;

  const float* fn = facts + n * SS * HH;
  const float* qn = questions + (n * SS + i0) * HH;
  const float* mn = prevM + (n * SS + i0) * HH;

  const f32x4 zero4 = {0.f, 0.f, 0.f, 0.f};
  f32x4 acc[4][4];
#pragma unroll
  for (int a = 0; a < 4; ++a)
#pragma unroll
    for (int b = 0; b < 4; ++b) acc[a][b] = zero4;

  float2 fv0, fv1, qv0, qv1, mv0, mv1;
  auto prefetch = [&](int hc) {
    const int h = hc * 32 + hh2;
    fv0 = *(const float2*)(fn + jb * HH + h);
    fv1 = *(const float2*)(fn + (jb + 32) * HH + h);
    qv0 = *(const float2*)(qn + h);
    qv1 = *(const float2*)(qn + HH + h);
    mv0 = *(const float2*)(mn + h);
    mv1 = *(const float2*)(mn + HH + h);
  };
  prefetch(0);

  for (int hc = 0; hc < 8; ++hc) {
    {
      float2 fl2[2] = {fv0, fv1}, ql2[2] = {qv0, qv1}, ml2[2] = {mv0, mv1};
#pragma unroll
      for (int pl = 0; pl < 2; ++pl) {
        const int j = jb + pl * 32;
#pragma unroll
        for (int il = 0; il < 2; ++il) {
          const int row = il * 64 + j;
          const float fx = fl2[pl].x, fy = fl2[pl].y;
          const float qx = ql2[il].x, qy = ql2[il].y;
          const float mx = ml2[il].x, my = ml2[il].y;
          *(unsigned int*)&A[row][0 * 32 + hh2] = pk2(fx * qx, fy * qy);
          *(unsigned int*)&A[row][1 * 32 + hh2] = pk2(fx * mx, fy * my);
          *(unsigned int*)&A[row][2 * 32 + hh2] = pk2(fabsf(fx - qx), fabsf(fy - qy));
          *(unsigned int*)&A[row][3 * 32 + hh2] = pk2(fabsf(fx - mx), fabsf(fy - my));
        }
      }
    }
    if (hc < 7) prefetch(hc + 1);
    __syncthreads();

    const unsigned short* bb = z1wbf + (cg * 64 + l15) * 1024 + hc * 32 + q * 8;
#pragma unroll
    for (int s = 0; s < 4; ++s) {
      short8 Bf[4];
#pragma unroll
      for (int nf = 0; nf < 4; ++nf)
        Bf[nf] = *(const short8*)(bb + (nf * 16) * 1024 + s * 256);
      short8 Af[4];
#pragma unroll
      for (int mf = 0; mf < 4; ++mf)
        Af[mf] = *(const short8*)&A[rg * 64 + mf * 16 + l15][s * 32 + q * 8];
#pragma unroll
      for (int mf = 0; mf < 4; ++mf)
#pragma unroll
        for (int nf = 0; nf < 4; ++nf)
          acc[mf][nf] = __builtin_amdgcn_mfma_f32_16x16x32_bf16(Af[mf], Bf[nf], acc[mf][nf], 0, 0, 0);
    }
    __syncthreads();
  }

  float psum[4][4];
#pragma unroll
  for (int mf = 0; mf < 4; ++mf)
#pragma unroll
    for (int v = 0; v < 4; ++v) psum[mf][v] = 0.f;

#pragma unroll
  for (int nf = 0; nf < 4; ++nf) {
    const int k = cg * 64 + nf * 16 + l15;
    const float zb = z1b[k], zw = z2w[k];
#pragma unroll
    for (int mf = 0; mf < 4; ++mf)
#pragma unroll
      for (int v = 0; v < 4; ++v) {
        const float x = acc[mf][nf][v] + zb;
        const float e = __expf(2.f * x);
        const float t = 1.f - 2.f / (e + 1.f);
        psum[mf][v] += zw * t;
      }
  }
#pragma unroll
  for (int d = 1; d < 16; d <<= 1)
#pragma unroll
    for (int mf = 0; mf < 4; ++mf)
#pragma unroll
      for (int v = 0; v < 4; ++v) psum[mf][v] += __shfl_xor(psum[mf][v], d, 64);
  if (l15 == 0) {
#pragma unroll
    for (int mf = 0; mf < 4; ++mf)
#pragma unroll
      for (int v = 0; v < 4; ++v)
        Gpart[rg * 64 + mf * 16 + q * 4 + v][cg] = psum[mf][v];
  }
  __syncthreads();
  if (tid < 128) {
    const float g = Gpart[tid][0] + Gpart[tid][1] + Gpart[tid][2] + Gpart[tid][3] + z2b[0];
    const int i = i0 + (tid >> 6), j = tid & 63;
    G[(n * SS + i) * SS + j] = g;
  }
}

// ---------------------------------------------------------------------------
// Phase A2: masked softmax over j. One wave per (n,i); lane = j.
// ---------------------------------------------------------------------------
__global__ void softmax_attn(const float* __restrict__ G, const int* __restrict__ doc_len,
                             float* __restrict__ attn) {
  const int gid = blockIdx.x * 256 + threadIdx.x;
  const int wid = gid >> 6, l = gid & 63;
  const int n = wid >> 6, i = wid & 63;
  const int dl = doc_len[n];
  const float g = G[(n * SS + i) * SS + l];
  const float x = (l < dl && g != 0.0f) ? g : -INFINITY;
  float mx = x;
#pragma unroll
  for (int d = 1; d < 64; d <<= 1) mx = fmaxf(mx, __shfl_xor(mx, d, 64));
  const float e = (x == -INFINITY) ? 0.f : __expf(x - mx);
  float s = e;
#pragma unroll
  for (int d = 1; d < 64; d <<= 1) s += __shfl_xor(s, d, 64);
  attn[(n * SS + i) * SS + l] = e / s;
}

// ---------------------------------------------------------------------------
// Phase C: GRU scan, 1 barrier/step. THE R5 CHANGE: B-fragments are defined
// by a one-time `asm volatile "+a"` before the t-loop. A volatile-asm def
// cannot be rematerialized, so the allocator MUST keep the 128 AGPRs live
// across the loop (R2-R4 failure mode: loop-invariant loads legally
// re-executed from L2 every step, ~1100+ cyc/step per XCD of L2 traffic).
// Budget: 128 AGPR + ~120 VGPR = 248 <= 256 unified regs/wave at waves/EU=2.
// ---------------------------------------------------------------------------
__global__ __launch_bounds__(512, 2) void gru_scan(
    const unsigned short* __restrict__ wcat, const float* __restrict__ FWr,
    const float* __restrict__ FW, const float* __restrict__ Ub,
    const float* __restrict__ attn, unsigned short* __restrict__ Cout) {
  __shared__ unsigned short Cbf[2][16 * 266];  // 133-word stride: conflict-free b128 reads
  __shared__ float attn_s[16 * 65];

  const int bi = blockIdx.x, n = bi >> 2, i0 = (bi & 3) * 16;
  const int tid = threadIdx.x, w = tid >> 6, l = tid & 63;
  const int l15 = l & 15, q = l >> 4;
  const int h0 = w * 32 + 2 * l15;  // true col of tile nf=0; nf=1 is h0+1

  // B-fragments, loaded once...
  short8 Br0[8], Br1[8], Bu0[8], Bu1[8];
  {
    const unsigned short* b0 = wcat + (w * 32 + l15) * 256 + q * 8;
#pragma unroll
    for (int kt = 0; kt < 8; ++kt) {
      Br0[kt] = *(const short8*)(b0 + kt * 32);
      Br1[kt] = *(const short8*)(b0 + 16 * 256 + kt * 32);
      Bu0[kt] = *(const short8*)(b0 + 256 * 256 + kt * 32);
      Bu1[kt] = *(const short8*)(b0 + 272 * 256 + kt * 32);
    }
  }
  // ...then pinned in AGPRs by a non-rematerializable volatile def.
#pragma unroll
  for (int kt = 0; kt < 8; ++kt)
    asm volatile("" : "+a"(Br0[kt]), "+a"(Br1[kt]), "+a"(Bu0[kt]), "+a"(Bu1[kt]));

  const float2 ub2 = *(const float2*)(Ub + h0);

  for (int e = tid; e < 16 * 64; e += 512)
    attn_s[(e >> 6) * 65 + (e & 63)] = attn[(n * SS + i0 + (e >> 6)) * SS + (e & 63)];
  for (int e = tid; e < (16 * 266) / 2; e += 512) ((unsigned int*)Cbf[0])[e] = 0u;
  __syncthreads();

  float Cf0[4] = {0.f, 0.f, 0.f, 0.f}, Cf1[4] = {0.f, 0.f, 0.f, 0.f};

  const float* fwr_g = FWr + (n * SS) * HH + h0;
  const float* fw_g  = FW + (n * SS) * HH + h0;
  float2 fwr2 = *(const float2*)(fwr_g);
  float2 fw2  = *(const float2*)(fw_g);

  for (int t = 0; t < 64; ++t) {
    // prefetch next step's per-col scalars early (drained at the barrier)
    const int tn = (t + 1) & 63;
    const float2 fwr2n = *(const float2*)(fwr_g + tn * HH);
    const float2 fw2n  = *(const float2*)(fw_g + tn * HH);

    const unsigned short* cb = Cbf[t & 1] + l15 * 266 + q * 8;
    short8 Af[8];
#pragma unroll
    for (int kt = 0; kt < 8; ++kt) Af[kt] = *(const short8*)(cb + kt * 32);

    f32x4 ar0 = {0.f, 0.f, 0.f, 0.f}, ar1 = ar0, au0 = ar0, au1 = ar0;
    // >=2-cycle gap between acc zero-init (VALU writes) and first MFMA read
    asm("s_nop 1" : "+v"(ar0), "+v"(ar1), "+v"(au0), "+v"(au1));
#pragma unroll
    for (int kt = 0; kt < 8; ++kt) {
      MFMA_BA(ar0, Af[kt], Br0[kt]);
      MFMA_BA(ar1, Af[kt], Br1[kt]);
      MFMA_BA(au0, Af[kt], Bu0[kt]);
      MFMA_BA(au1, Af[kt], Bu1[kt]);
    }
    // MFMA dest -> VALU read hazard guard (ordered via operand dataflow)
    asm("s_nop 7\n\ts_nop 7" : "+v"(ar0), "+v"(ar1), "+v"(au0), "+v"(au1));

    unsigned short* cw = Cbf[(t + 1) & 1];
#pragma unroll
    for (int v = 0; v < 4; ++v) {
      const int row = q * 4 + v;
      const float g = attn_s[row * 65 + t];
      float cn0, cn1;
      {
        const float r  = 1.f / (1.f + __expf(-(fwr2.x + ar0[v])));
        const float x  = fw2.x + r * (au0[v] + ub2.x);
        const float eh = __expf(2.f * x);
        const float ht = 1.f - 2.f / (eh + 1.f);
        cn0 = g * ht + (1.f - g) * Cf0[v];
        Cf0[v] = cn0;
      }
      {
        const float r  = 1.f / (1.f + __expf(-(fwr2.y + ar1[v])));
        const float x  = fw2.y + r * (au1[v] + ub2.y);
        const float eh = __expf(2.f * x);
        const float ht = 1.f - 2.f / (eh + 1.f);
        cn1 = g * ht + (1.f - g) * Cf1[v];
        Cf1[v] = cn1;
      }
      *(unsigned int*)&cw[row * 266 + h0] = pk2(cn0, cn1);
    }
    fwr2 = fwr2n;
    fw2 = fw2n;
    __syncthreads();
  }

  // final C (bf16) for phase D, true col order
#pragma unroll
  for (int v = 0; v < 4; ++v) {
    const int row = i0 + q * 4 + v;
    *(unsigned int*)&Cout[(n * SS + row) * HH + h0] = pk2(Cf0[v], Cf1[v]);
  }
}

// ---------------------------------------------------------------------------
// Phase D: next_mem = relu([prevM | C | questions] @ nm_w^T + nm_b)
// ---------------------------------------------------------------------------
__global__ __launch_bounds__(256) void next_mem_gemm(
    const unsigned short* __restrict__ pmbf, const unsigned short* __restrict__ cbf,
    const unsigned short* __restrict__ qbf, const unsigned short* __restrict__ nmbf,
    const float* __restrict__ nmb, float* __restrict__ out) {
  __shared__ unsigned short A[64][40];
  const int bi = blockIdx.x;
  const int rb = bi >> 2, cb = bi & 3;
  const int r0 = rb * 64, c0 = cb * 64;
  const int tid = threadIdx.x, w = tid >> 6, l = tid & 63;
  const int l15 = l & 15, q = l >> 4;

  f32x4 acc[4];
  const f32x4 z4 = {0.f, 0.f, 0.f, 0.f};
#pragma unroll
  for (int nf = 0; nf < 4; ++nf) acc[nf] = z4;

  for (int kt = 0; kt < 24; ++kt) {
    const int kg = kt * 32;
    const unsigned short* src =
        kg < 256 ? (pmbf + kg) : (kg < 512 ? (cbf + kg - 256) : (qbf + kg - 512));
    const int kk = (tid & 15) * 2;
#pragma unroll
    for (int ps = 0; ps < 4; ++ps) {
      const int row = ps * 16 + (tid >> 4);
      *(unsigned int*)&A[row][kk] = *(const unsigned int*)(src + (r0 + row) * HH + kk);
    }
    __syncthreads();
    short8 Bfr[4];
#pragma unroll
    for (int nf = 0; nf < 4; ++nf)
      Bfr[nf] = *(const short8*)(nmbf + (c0 + nf * 16 + l15) * 768 + kg + q * 8);
    const short8 Af = *(const short8*)&A[w * 16 + l15][q * 8];
#pragma unroll
    for (int nf = 0; nf < 4; ++nf)
      acc[nf] = __builtin_amdgcn_mfma_f32_16x16x32_bf16(Af, Bfr[nf], acc[nf], 0, 0, 0);
    __syncthreads();
  }
#pragma unroll
  for (int nf = 0; nf < 4; ++nf) {
    const int col = c0 + nf * 16 + l15;
    const float bv = nmb[col];
#pragma unroll
    for (int v = 0; v < 4; ++v) {
      const int grow = r0 + w * 16 + q * 4 + v;
      out[grow * HH + col] = fmaxf(acc[nf][v] + bv, 0.f);
    }
  }
}

// ---------------------------------------------------------------------------
extern "C" void kernel_launch(void* const* d_in, const int* in_sizes, int n_in,
                              void* d_out, int out_size, void* d_ws, size_t ws_size,
                              hipStream_t stream) {
  const float* facts     = (const float*)d_in[0];
  const float* prevM     = (const float*)d_in[1];
  const float* questions = (const float*)d_in[2];
  const int*   doc_len   = (const int*)d_in[3];
  const float* z1w = (const float*)d_in[4];
  const float* z1b = (const float*)d_in[5];
  const float* z2w = (const float*)d_in[6];
  const float* z2b = (const float*)d_in[7];
  const float* Wrw = (const float*)d_in[8];
  const float* Wrb = (const float*)d_in[9];
  const float* Urw = (const float*)d_in[10];
  const float* Urb = (const float*)d_in[11];
  const float* Ww  = (const float*)d_in[12];
  const float* Wb  = (const float*)d_in[13];
  const float* Uw  = (const float*)d_in[14];
  const float* Ub  = (const float*)d_in[15];
  const float* nmw = (const float*)d_in[16];
  const float* nmb = (const float*)d_in[17];

  char* ws = (char*)d_ws;
  unsigned short* z1wbf  = (unsigned short*)(ws + 0);        // 512 KB
  unsigned short* wcatbf = (unsigned short*)(ws + 524288);   // 256 KB
  unsigned short* nmbf   = (unsigned short*)(ws + 786432);   // 384 KB
  unsigned short* pmbf   = (unsigned short*)(ws + 1179648);  // 512 KB
  unsigned short* qbf    = (unsigned short*)(ws + 1703936);  // 512 KB
  float* G   = (float*)(ws + 2228224);                       // 256 KB
  float* FWr = (float*)(ws + 2490368);                       // 1 MB
  float* FW  = (float*)(ws + 3538944);                       // 1 MB
  unsigned short* cbf = (unsigned short*)(ws + 4587520);     // 512 KB

  float* out  = (float*)d_out;
  float* attn = out + NB * SS * HH;

  prolog_cvt<<<4352, 256, 0, stream>>>(z1w, Urw, Uw, nmw, prevM, questions,
                                       z1wbf, wcatbf, nmbf, pmbf, qbf);
  fact_proj<<<256, 256, 0, stream>>>(facts, Wrw, Wrb, Urb, Ww, Wb, FWr, FW);
  gate_gemm<<<512, 512, 0, stream>>>(facts, prevM, questions, z1wbf, z1b, z2w, z2b, G);
  softmax_attn<<<256, 256, 0, stream>>>(G, doc_len, attn);
  gru_scan<<<64, 512, 0, stream>>>(wcatbf, FWr, FW, Ub, attn, cbf);
  next_mem_gemm<<<64, 256, 0, stream>>>(pmbf, cbf, qbf, nmbf, nmb, out);
}